// Round 4
// baseline (997.786 us; speedup 1.0000x reference)
//
#include <hip/hip_runtime.h>

// GRU_27212912787836 : 2-layer GRU, B=512, T=1024, IN=3, H=64 (fp32 in/out)
// bf16 MFMA internally, fp32 cell math/state.
//
// Round 7: layer-decoupled blocks. 128 L0-blocks + 128 L1-blocks, 256 thr
// (4 waves) each -> 1 wave/SIMD on all 256 CUs. Each block keeps the
// 4-batch M-row packing (batches at M-rows {0,4,8,12}; lane (grp,c) owns
// batch grp, feature jt*16+c; comp[0] only). Intra-layer h exchange:
// LDS double-buffer + per-step s_barrier (4 waves). L0->L1 handoff:
// global bf16 ring in d_ws, depth D (pow2, up to T), relaxed AGENT-scope
// atomics (L2-bypass -> coherent at IF across XCDs); L0 publishes prog0
// every 8 steps after an explicit vmcnt(0) drain; L1 spins rarely (L0,
// with 6 MFMAs/step vs L1's 12, runs ahead; with D=T it never waits).
// WAR guard (prog1) only active when D < T. Deadlock-free: all 256 blocks
// are co-resident (capacity >= 1 block/CU), and with D=T L0 depends on
// nothing. Fallback: if ws too small, launch the round-5 kernel (424 us).

typedef __attribute__((ext_vector_type(8))) short short8;     // 8 bf16
typedef __attribute__((ext_vector_type(4))) float floatx4;    // MFMA C/D
typedef __attribute__((ext_vector_type(4))) unsigned uintx4;  // 4 dwords

#define MFMA16(a, b, c) __builtin_amdgcn_mfma_f32_16x16x32_bf16((a), (b), (c), 0, 0, 0)

static constexpr int kB = 512;
static constexpr int kT = 1024;
static constexpr int kIN = 3;
static constexpr int kH = 64;
static constexpr int LDH = 72;  // padded LDS row stride (bf16)
static constexpr float kL2E = 1.44269504f;

__device__ __forceinline__ unsigned short f2bf(float f) {
  unsigned u = __builtin_bit_cast(unsigned, f);
  return (unsigned short)((u + 0x7FFFu + ((u >> 16) & 1u)) >> 16);
}
__device__ __forceinline__ short8 cvt8s(const float* p, float s) {
  short8 f;
#pragma unroll
  for (int j = 0; j < 8; ++j) f[j] = (short)f2bf(p[j] * s);
  return f;
}

// LDS-only drain + barrier: global ops stay in flight.
#define BLOCK_SYNC() asm volatile("s_waitcnt lgkmcnt(0)\n\ts_barrier" ::: "memory")

__global__ __launch_bounds__(256, 1) void gru_pipe(
    const float* __restrict__ x,
    const float* __restrict__ Wih0, const float* __restrict__ Whh0,
    const float* __restrict__ bih0, const float* __restrict__ bhh0,
    const float* __restrict__ Wih1, const float* __restrict__ Whh1,
    const float* __restrict__ bih1, const float* __restrict__ bhh1,
    float* __restrict__ out, unsigned* __restrict__ flags,
    unsigned* __restrict__ ring, int D) {
  const int tid  = threadIdx.x;
  const int lane = tid & 63;
  const int jt   = tid >> 6;       // wave = feature tile 0..3
  const int c    = lane & 15;
  const int grp  = lane >> 4;      // batch index within block / K-chunk on reads
  const int f    = jt * 16 + c;    // feature owned by this lane
  const bool isL1 = blockIdx.x >= 128;
  const int pair = isL1 ? (int)blockIdx.x - 128 : (int)blockIdx.x;
  const int b    = pair * 4 + grp; // batch owned by this lane
  const bool wrap = (D < kT);

  unsigned* prog0 = flags + pair * 32;       // steps published by L0
  unsigned* prog1 = flags + pair * 32 + 16;  // steps consumed by L1 (wrap only)
  unsigned* rbase = ring + (size_t)pair * D * 128;  // 512B slots (128 dwords)

  __shared__ __align__(16) unsigned short lds[2][16 * LDH];
  {
    unsigned short* z = &lds[0][0];
    for (int i = tid; i < 2 * 16 * LDH; i += 256) z[i] = 0;
  }
  __syncthreads();  // once

  const float gsc[3] = {-kL2E, -kL2E, 2.0f * kL2E};
  const floatx4 Z = {0.f, 0.f, 0.f, 0.f};

  if (!isL1) {
    // ======================= LAYER-0 block =======================
    short8 wh[3][2];
    float wx[3][3];
#pragma unroll
    for (int g = 0; g < 3; ++g) {
      const int row = g * 64 + f;
      wh[g][0] = cvt8s(Whh0 + row * 64 + grp * 8, gsc[g]);
      wh[g][1] = cvt8s(Whh0 + row * 64 + 32 + grp * 8, gsc[g]);
#pragma unroll
      for (int i = 0; i < 3; ++i) wx[g][i] = Wih0[row * 3 + i] * gsc[g];
    }
    const float br  = gsc[0] * (bih0[f] + bhh0[f]);
    const float bz  = gsc[1] * (bih0[64 + f] + bhh0[64 + f]);
    const float bnx = gsc[2] * bih0[128 + f];
    const float bnh = gsc[2] * bhh0[128 + f];

    const float* xb = x + (size_t)b * kT * kIN;
    float cx0 = xb[0], cx1 = xb[1], cx2 = xb[2];
    float gxr = fmaf(wx[0][0], cx0, fmaf(wx[0][1], cx1, fmaf(wx[0][2], cx2, br)));
    float gxz = fmaf(wx[1][0], cx0, fmaf(wx[1][1], cx1, fmaf(wx[1][2], cx2, bz)));
    float gxn = fmaf(wx[2][0], cx0, fmaf(wx[2][1], cx1, fmaf(wx[2][2], cx2, bnx)));
    float nx0 = xb[3], nx1 = xb[4], nx2 = xb[5];

    short8 a0 = {0, 0, 0, 0, 0, 0, 0, 0}, a1 = a0;  // h0(t-1) A-frags
    float hp = 0.f;
    unsigned cons = 0;

#pragma unroll 1
    for (int t = 0; t < kT; ++t) {
      floatx4 pr = MFMA16(a0, wh[0][0], Z); pr = MFMA16(a1, wh[0][1], pr);
      floatx4 pz = MFMA16(a0, wh[1][0], Z); pz = MFMA16(a1, wh[1][1], pz);
      floatx4 pn = MFMA16(a0, wh[2][0], Z); pn = MFMA16(a1, wh[2][1], pn);

      const float ar = pr[0] + gxr;
      const float az = pz[0] + gxz;
      float r_ = __builtin_amdgcn_rcpf(1.0f + __builtin_amdgcn_exp2f(ar));
      float z_ = __builtin_amdgcn_rcpf(1.0f + __builtin_amdgcn_exp2f(az));
      float u  = __builtin_amdgcn_rcpf(1.0f + __builtin_amdgcn_exp2f(gxn + r_ * (pn[0] + bnh)));
      float ng = 1.0f - 2.0f * u;
      float hn = ng + z_ * (hp - ng);
      hp = hn;

      const unsigned hb = f2bf(hn);
      lds[t & 1][(4 * grp) * LDH + f] = (unsigned short)hb;

      // WAR guard (only when ring shorter than T)
      if (wrap && t >= D) {
        while (cons + (unsigned)D < (unsigned)t + 1u)
          cons = __hip_atomic_load(prog1, __ATOMIC_RELAXED, __HIP_MEMORY_SCOPE_AGENT);
      }
      // publish h0(t) to the ring: packed dword, even-c lanes, L2-bypass
      const unsigned ov = (unsigned)__shfl_xor((int)hb, 1);
      if ((c & 1) == 0)
        __hip_atomic_store(rbase + (size_t)(t & (D - 1)) * 128 + grp * 32 + jt * 8 + (c >> 1),
                           hb | (ov << 16), __ATOMIC_RELAXED, __HIP_MEMORY_SCOPE_AGENT);

      // x-part for t+1 (off critical path), then prefetch x(t+2)
      gxr = fmaf(wx[0][0], nx0, fmaf(wx[0][1], nx1, fmaf(wx[0][2], nx2, br)));
      gxz = fmaf(wx[1][0], nx0, fmaf(wx[1][1], nx1, fmaf(wx[1][2], nx2, bz)));
      gxn = fmaf(wx[2][0], nx0, fmaf(wx[2][1], nx1, fmaf(wx[2][2], nx2, bnx)));
      if (t + 2 < kT) {
        const float* p = xb + (size_t)(t + 2) * kIN;
        nx0 = p[0]; nx1 = p[1]; nx2 = p[2];
      }

      const bool pub = ((t & 7) == 7) || (t == kT - 1);
      if (pub) asm volatile("s_waitcnt vmcnt(0)" ::: "memory");  // ring stores done
      BLOCK_SYNC();
      if (pub && tid == 0)
        __hip_atomic_store(prog0, (unsigned)(t + 1), __ATOMIC_RELAXED, __HIP_MEMORY_SCOPE_AGENT);

      if (t + 1 < kT) {
        const unsigned short* s = &lds[t & 1][0];
        a0 = *(const short8*)(s + c * LDH + grp * 8);
        a1 = *(const short8*)(s + c * LDH + 32 + grp * 8);
      }
    }
  } else {
    // ======================= LAYER-1 block =======================
    short8 wi[3][2], wh[3][2];
#pragma unroll
    for (int g = 0; g < 3; ++g) {
      const int row = g * 64 + f;
      wi[g][0] = cvt8s(Wih1 + row * 64 + grp * 8, gsc[g]);
      wi[g][1] = cvt8s(Wih1 + row * 64 + 32 + grp * 8, gsc[g]);
      wh[g][0] = cvt8s(Whh1 + row * 64 + grp * 8, gsc[g]);
      wh[g][1] = cvt8s(Whh1 + row * 64 + 32 + grp * 8, gsc[g]);
    }
    const float b1r  = gsc[0] * (bih1[f] + bhh1[f]);
    const float b1z  = gsc[1] * (bih1[64 + f] + bhh1[64 + f]);
    const float b1nx = gsc[2] * bih1[128 + f];
    const float b1nh = gsc[2] * bhh1[128 + f];

    const bool act = ((c & 3) == 0);  // A rows c%4==0 carry batch c>>2
    const int bat = c >> 2;
    short8 zf = {0, 0, 0, 0, 0, 0, 0, 0};
    short8 cur0 = zf, cur1 = zf, nxt0 = zf, nxt1 = zf;
    short8 h1a0 = zf, h1a1 = zf;
    float hp = 0.f;
    unsigned avail = 0;
    float* ob = out + (size_t)b * kT * kH + f;
    const size_t FH = (size_t)kB * kT * kH;

    auto load_slot = [&](int s, short8& o0, short8& o1) {
      if (act) {
        const unsigned* dp = rbase + (size_t)(s & (D - 1)) * 128 + bat * 32 + grp * 4;
        uintx4 w0, w1;
#pragma unroll
        for (int j = 0; j < 4; ++j)
          w0[j] = __hip_atomic_load(dp + j, __ATOMIC_RELAXED, __HIP_MEMORY_SCOPE_AGENT);
#pragma unroll
        for (int j = 0; j < 4; ++j)
          w1[j] = __hip_atomic_load(dp + 16 + j, __ATOMIC_RELAXED, __HIP_MEMORY_SCOPE_AGENT);
        o0 = __builtin_bit_cast(short8, w0);
        o1 = __builtin_bit_cast(short8, w1);
      }
    };

    // warmup: h0(0)
    while (avail < 1u)
      avail = __hip_atomic_load(prog0, __ATOMIC_RELAXED, __HIP_MEMORY_SCOPE_AGENT);
    load_slot(0, cur0, cur1);

#pragma unroll 1
    for (int t = 0; t < kT; ++t) {
      // x-part first: cur frags in regs, no dependence on this step's exchange
      floatx4 qr = MFMA16(cur0, wi[0][0], Z); qr = MFMA16(cur1, wi[0][1], qr);
      floatx4 qz = MFMA16(cur0, wi[1][0], Z); qz = MFMA16(cur1, wi[1][1], qz);
      floatx4 qn = MFMA16(cur0, wi[2][0], Z); qn = MFMA16(cur1, wi[2][1], qn);
      // h-part
      floatx4 pr = MFMA16(h1a0, wh[0][0], Z); pr = MFMA16(h1a1, wh[0][1], pr);
      floatx4 pz = MFMA16(h1a0, wh[1][0], Z); pz = MFMA16(h1a1, wh[1][1], pz);
      floatx4 pn = MFMA16(h1a0, wh[2][0], Z); pn = MFMA16(h1a1, wh[2][1], pn);

      // prefetch h0(t+1) under the MFMAs (flag check amortized: prog0 jumps by 8)
      if (t + 1 < kT) {
        if (avail < (unsigned)t + 2u) {
          do {
            avail = __hip_atomic_load(prog0, __ATOMIC_RELAXED, __HIP_MEMORY_SCOPE_AGENT);
          } while (avail < (unsigned)t + 2u);
        }
        load_slot(t + 1, nxt0, nxt1);
      }

      const float ar = pr[0] + qr[0] + b1r;
      const float az = pz[0] + qz[0] + b1z;
      float r_ = __builtin_amdgcn_rcpf(1.0f + __builtin_amdgcn_exp2f(ar));
      float z_ = __builtin_amdgcn_rcpf(1.0f + __builtin_amdgcn_exp2f(az));
      float u  = __builtin_amdgcn_rcpf(1.0f + __builtin_amdgcn_exp2f(qn[0] + b1nx + r_ * (pn[0] + b1nh)));
      float ng = 1.0f - 2.0f * u;
      float hn = ng + z_ * (hp - ng);
      hp = hn;

      ob[(size_t)t * kH] = hn;  // stays in flight; no vmcnt drain in loop
      if (t == kT - 1) out[FH + (size_t)b * kH + f] = hn;

      lds[t & 1][(4 * grp) * LDH + f] = f2bf(hn);

      if (wrap && (t & 7) == 7) asm volatile("s_waitcnt vmcnt(0)" ::: "memory");
      BLOCK_SYNC();
      if (wrap && (t & 7) == 7 && tid == 0)
        __hip_atomic_store(prog1, (unsigned)t, __ATOMIC_RELAXED, __HIP_MEMORY_SCOPE_AGENT);

      if (t + 1 < kT) {
        const unsigned short* s = &lds[t & 1][0];
        h1a0 = *(const short8*)(s + c * LDH + grp * 8);
        h1a1 = *(const short8*)(s + c * LDH + 32 + grp * 8);
        cur0 = nxt0; cur1 = nxt1;
      }
    }
  }
}

// ---------------- fallback: round-5 kernel (no workspace), 424 us ----------------
__global__ __launch_bounds__(512, 2) void gru_small(
    const float* __restrict__ x,
    const float* __restrict__ Wih0, const float* __restrict__ Whh0,
    const float* __restrict__ bih0, const float* __restrict__ bhh0,
    const float* __restrict__ Wih1, const float* __restrict__ Whh1,
    const float* __restrict__ bih1, const float* __restrict__ bhh1,
    float* __restrict__ out) {
  const int tid  = threadIdx.x;
  const int lane = tid & 63;
  const int jt   = (tid >> 6) & 3;
  const int lyr  = tid >> 8;
  const int c    = lane & 15;
  const int grp  = lane >> 4;
  const int wb   = blockIdx.x * 4;

  __shared__ unsigned short h0buf[2][16 * LDH];
  __shared__ unsigned short h1buf[2][16 * LDH];
  {
    unsigned short* z0 = &h0buf[0][0];
    unsigned short* z1 = &h1buf[0][0];
    for (int i = tid; i < 2 * 16 * LDH; i += 512) { z0[i] = 0; z1[i] = 0; }
  }
  __syncthreads();

  const int gr = jt * 16 + c, gz = 64 + gr, gn = 128 + gr;
  const float gsc[3] = {-kL2E, -kL2E, 2.0f * kL2E};
  const int myrow = grp * 4;

  if (lyr == 0) {
    short8 whh0[2][3], wxm[3];
#pragma unroll
    for (int g = 0; g < 3; ++g) {
      const int off = ((g * 4 + jt) * 16 + c) * kH + grp * 8;
      whh0[0][g] = cvt8s(Whh0 + off, gsc[g]);
      whh0[1][g] = cvt8s(Whh0 + off + 32, gsc[g]);
      short8 fv = {0, 0, 0, 0, 0, 0, 0, 0};
      if (grp == 0) {
        const float* p = Wih0 + ((g * 4 + jt) * 16 + c) * kIN;
        fv[0] = (short)f2bf(p[0] * gsc[g]);
        fv[1] = (short)f2bf(p[1] * gsc[g]);
        fv[2] = (short)f2bf(p[2] * gsc[g]);
      }
      wxm[g] = fv;
    }
    const float b0r  = gsc[0] * (bih0[gr] + bhh0[gr]);
    const float b0z  = gsc[1] * (bih0[gz] + bhh0[gz]);
    const float b0nx = gsc[2] * bih0[gn];
    const float b0nh = gsc[2] * bhh0[gn];

    float h0D = 0.f;
    short8 h0A0 = {0, 0, 0, 0, 0, 0, 0, 0}, h0A1 = h0A0;

    auto load_x = [&](int t) -> short8 {
      short8 fv = {0, 0, 0, 0, 0, 0, 0, 0};
      if (grp == 0 && (c & 3) == 0) {
        const float* p = x + ((size_t)(wb + (c >> 2)) * kT + t) * kIN;
        fv[0] = (short)f2bf(p[0]); fv[1] = (short)f2bf(p[1]); fv[2] = (short)f2bf(p[2]);
      }
      return fv;
    };
    short8 xf = load_x(0);

#pragma unroll 1
    for (int t = 0; t <= kT; ++t) {
      if (t < kT) {
        floatx4 pr = {b0r, b0r, b0r, b0r};
        pr = MFMA16(xf, wxm[0], pr);
        pr = MFMA16(h0A0, whh0[0][0], pr);
        floatx4 qr = {0.f, 0.f, 0.f, 0.f};
        qr = MFMA16(h0A1, whh0[1][0], qr);
        floatx4 pz = {b0z, b0z, b0z, b0z};
        pz = MFMA16(xf, wxm[1], pz);
        pz = MFMA16(h0A0, whh0[0][1], pz);
        floatx4 qz = {0.f, 0.f, 0.f, 0.f};
        qz = MFMA16(h0A1, whh0[1][1], qz);
        floatx4 px = {b0nx, b0nx, b0nx, b0nx};
        px = MFMA16(xf, wxm[2], px);
        floatx4 ph = {b0nh, b0nh, b0nh, b0nh};
        ph = MFMA16(h0A0, whh0[0][2], ph);
        ph = MFMA16(h0A1, whh0[1][2], ph);

        short8 xn = load_x(t + 1 < kT ? t + 1 : t);

        const float ar = pr[0] + qr[0], az = pz[0] + qz[0];
        float r_ = __builtin_amdgcn_rcpf(1.0f + __builtin_amdgcn_exp2f(ar));
        float z_ = __builtin_amdgcn_rcpf(1.0f + __builtin_amdgcn_exp2f(az));
        float u  = __builtin_amdgcn_rcpf(1.0f + __builtin_amdgcn_exp2f(px[0] + r_ * ph[0]));
        float ng = 1.0f - 2.0f * u;
        float hn = ng + z_ * (h0D - ng);
        h0D = hn;
        h0buf[t & 1][myrow * LDH + jt * 16 + c] = f2bf(hn);
        xf = xn;
      }
      BLOCK_SYNC();
      if (t < kT - 1) {
        const unsigned short* s = h0buf[t & 1];
        h0A0 = *(const short8*)(s + c * LDH + grp * 8);
        h0A1 = *(const short8*)(s + c * LDH + 32 + grp * 8);
      }
    }
  } else {
    short8 wih1[2][3], whh1[2][3];
#pragma unroll
    for (int g = 0; g < 3; ++g) {
      const int off = ((g * 4 + jt) * 16 + c) * kH + grp * 8;
      wih1[0][g] = cvt8s(Wih1 + off, gsc[g]);
      wih1[1][g] = cvt8s(Wih1 + off + 32, gsc[g]);
      whh1[0][g] = cvt8s(Whh1 + off, gsc[g]);
      whh1[1][g] = cvt8s(Whh1 + off + 32, gsc[g]);
    }
    const float b1r  = gsc[0] * (bih1[gr] + bhh1[gr]);
    const float b1z  = gsc[1] * (bih1[gz] + bhh1[gz]);
    const float b1nx = gsc[2] * bih1[gn];
    const float b1nh = gsc[2] * bhh1[gn];

    float h1D = 0.f;
    short8 h1A0 = {0, 0, 0, 0, 0, 0, 0, 0}, h1A1 = h1A0;

    const size_t FH = (size_t)kB * kT * kH;
    float* obase = out + (size_t)(wb + grp) * kT * kH + jt * 16 + c;

#pragma unroll 1
    for (int t = 0; t <= kT; ++t) {
      if (t >= 1) {
        const unsigned short* s0 = h0buf[(t - 1) & 1];
        short8 x0 = *(const short8*)(s0 + c * LDH + grp * 8);
        short8 x1 = *(const short8*)(s0 + c * LDH + 32 + grp * 8);

        floatx4 pr = {b1r, b1r, b1r, b1r};
        pr = MFMA16(h1A0, whh1[0][0], pr);
        pr = MFMA16(h1A1, whh1[1][0], pr);
        floatx4 pz = {b1z, b1z, b1z, b1z};
        pz = MFMA16(h1A0, whh1[0][1], pz);
        pz = MFMA16(h1A1, whh1[1][1], pz);
        floatx4 pnh = {b1nh, b1nh, b1nh, b1nh};
        pnh = MFMA16(h1A0, whh1[0][2], pnh);
        pnh = MFMA16(h1A1, whh1[1][2], pnh);

        floatx4 qr = {0.f, 0.f, 0.f, 0.f};
        qr = MFMA16(x0, wih1[0][0], qr);
        qr = MFMA16(x1, wih1[1][0], qr);
        floatx4 qz = {0.f, 0.f, 0.f, 0.f};
        qz = MFMA16(x0, wih1[0][1], qz);
        qz = MFMA16(x1, wih1[1][1], qz);
        floatx4 qnx = {b1nx, b1nx, b1nx, b1nx};
        qnx = MFMA16(x0, wih1[0][2], qnx);
        qnx = MFMA16(x1, wih1[1][2], qnx);

        const float ar = pr[0] + qr[0], az = pz[0] + qz[0];
        float r_ = __builtin_amdgcn_rcpf(1.0f + __builtin_amdgcn_exp2f(ar));
        float z_ = __builtin_amdgcn_rcpf(1.0f + __builtin_amdgcn_exp2f(az));
        float u  = __builtin_amdgcn_rcpf(1.0f + __builtin_amdgcn_exp2f(qnx[0] + r_ * pnh[0]));
        float ng = 1.0f - 2.0f * u;
        float hn = ng + z_ * (h1D - ng);
        h1D = hn;
        h1buf[t & 1][myrow * LDH + jt * 16 + c] = f2bf(hn);

        obase[(size_t)(t - 1) * kH] = hn;
        if (t == kT) out[FH + (size_t)(wb + grp) * kH + jt * 16 + c] = hn;
      }
      BLOCK_SYNC();
      if (t >= 1 && t < kT) {
        const unsigned short* s1r = h1buf[t & 1];
        h1A0 = *(const short8*)(s1r + c * LDH + grp * 8);
        h1A1 = *(const short8*)(s1r + c * LDH + 32 + grp * 8);
      }
    }
  }
}

extern "C" void kernel_launch(void* const* d_in, const int* in_sizes, int n_in,
                              void* d_out, int out_size, void* d_ws, size_t ws_size,
                              hipStream_t stream) {
  const float* xp   = (const float*)d_in[0];
  const float* wih0 = (const float*)d_in[1];
  const float* whh0 = (const float*)d_in[2];
  const float* bih0 = (const float*)d_in[3];
  const float* bhh0 = (const float*)d_in[4];
  const float* wih1 = (const float*)d_in[5];
  const float* whh1 = (const float*)d_in[6];
  const float* bih1 = (const float*)d_in[7];
  const float* bhh1 = (const float*)d_in[8];
  float* outp = (float*)d_out;

  const size_t FLAGB = 16384;                       // 128 pairs x 128B
  const size_t perDepth = (size_t)128 * 512;        // bytes per depth unit
  size_t availB = (ws_size > FLAGB) ? ws_size - FLAGB : 0;
  int maxD = (int)(availB / perDepth);

  if (d_ws != nullptr && maxD >= 8) {
    int D = 8;
    while (D * 2 <= maxD && D < kT) D *= 2;         // pow2, up to T
    hipMemsetAsync(d_ws, 0, FLAGB, stream);         // reset flags (graph-safe)
    unsigned* flags = (unsigned*)d_ws;
    unsigned* ring  = (unsigned*)((char*)d_ws + FLAGB);
    hipLaunchKernelGGL(gru_pipe, dim3(256), dim3(256), 0, stream,
                       xp, wih0, whh0, bih0, bhh0, wih1, whh1, bih1, bhh1,
                       outp, flags, ring, D);
  } else {
    hipLaunchKernelGGL(gru_small, dim3(kB / 4), dim3(512), 0, stream,
                       xp, wih0, whh0, bih0, bhh0, wih1, whh1, bih1, bhh1, outp);
  }
}

// Round 5
// 494.476 us; speedup vs baseline: 2.0179x; 2.0179x over previous
//
#include <hip/hip_runtime.h>

// GRU_27212912787836 : 2-layer GRU, B=512, T=1024, IN=3, H=64 (fp32 in/out)
// bf16 MFMA internally, fp32 cell math/state.
//
// Round 8: merged-layer waves. 128 blocks x 256 thr (4 waves, 1 wave/SIMD).
// Block owns 4 batches at MFMA M-rows {0,4,8,12}; wave jt owns feature tile
// jt*16..jt*16+15 for BOTH layers. Key: at round t, L0-hh and L1-ih consume
// the SAME h0(t-1) A-fragments, and L1-hh consumes h1(t-2) fragments -- all
// read right after the PREVIOUS barrier, so every one of the 18 MFMAs per
// wave has register-ready operands at round start. One 4-wave s_barrier per
// round (lgkmcnt-only drain; global stores stay in flight). L0 cell math
// co-issues on the VALU pipe under L1's MFMA matrix-pipe time.
//   round t: h0(t) = GRU0(h0(t-1), x(t)); h1(t-1) = GRU1(h1(t-2), h0(t-1))
// Loop peeled into round 0 / 1..T-1 (branchless) / T.
// x-part of L0 = 9 scalar fp32 FMAs (no MFMA); Z-trick accumulators; gate
// scales folded into weights/biases (sigma/tanh via exp2+rcp).

typedef __attribute__((ext_vector_type(8))) short short8;   // 8 bf16
typedef __attribute__((ext_vector_type(4))) float floatx4;  // MFMA C/D

#define MFMA16(a, b, c) __builtin_amdgcn_mfma_f32_16x16x32_bf16((a), (b), (c), 0, 0, 0)

static constexpr int kB = 512;
static constexpr int kT = 1024;
static constexpr int kIN = 3;
static constexpr int kH = 64;
static constexpr int LDH = 72;  // padded LDS row stride (bf16); rows 16B-aligned
static constexpr float kL2E = 1.44269504f;

__device__ __forceinline__ unsigned short f2bf(float f) {
  unsigned u = __builtin_bit_cast(unsigned, f);
  return (unsigned short)((u + 0x7FFFu + ((u >> 16) & 1u)) >> 16);
}
__device__ __forceinline__ short8 cvt8s(const float* p, float s) {
  short8 f;
#pragma unroll
  for (int j = 0; j < 8; ++j) f[j] = (short)f2bf(p[j] * s);
  return f;
}
__device__ __forceinline__ float sig2(float a) {  // sigma of pre-scaled acc
  return __builtin_amdgcn_rcpf(1.0f + __builtin_amdgcn_exp2f(a));
}

// LDS-only drain + barrier: global ops stay in flight.
#define BLOCK_SYNC() asm volatile("s_waitcnt lgkmcnt(0)\n\ts_barrier" ::: "memory")

__global__ __launch_bounds__(256, 1) void gru_kernel(
    const float* __restrict__ x,
    const float* __restrict__ Wih0, const float* __restrict__ Whh0,
    const float* __restrict__ bih0, const float* __restrict__ bhh0,
    const float* __restrict__ Wih1, const float* __restrict__ Whh1,
    const float* __restrict__ bih1, const float* __restrict__ bhh1,
    float* __restrict__ out) {
  const int tid  = threadIdx.x;
  const int lane = tid & 63;
  const int jt   = tid >> 6;      // wave = feature tile 0..3
  const int c    = lane & 15;
  const int grp  = lane >> 4;     // batch index within block (M-row 4*grp)
  const int f    = jt * 16 + c;   // feature owned by this lane
  const int b    = blockIdx.x * 4 + grp;

  __shared__ __align__(16) unsigned short h0buf[2][16 * LDH];
  __shared__ __align__(16) unsigned short h1buf[2][16 * LDH];
  {  // zero once: A-rows != 0 mod 4 must read 0 forever; h1buf[0]=h1(-1)=0
    unsigned short* z0 = &h0buf[0][0];
    unsigned short* z1 = &h1buf[0][0];
    for (int i = tid; i < 2 * 16 * LDH; i += 256) { z0[i] = 0; z1[i] = 0; }
  }
  __syncthreads();  // once, outside the loop

  const float gsc[3] = {-kL2E, -kL2E, 2.0f * kL2E};
  const floatx4 Z = {0.f, 0.f, 0.f, 0.f};

  // ---- weights (B-fragments, pre-scaled bf16; proven R2/R5 layout) ----
  short8 wh0[3][2], wi1[3][2], wh1[3][2];
  float wx[3][3];
#pragma unroll
  for (int g = 0; g < 3; ++g) {
    const int row = g * 64 + f;
#pragma unroll
    for (int k = 0; k < 2; ++k) {
      wh0[g][k] = cvt8s(Whh0 + row * kH + k * 32 + grp * 8, gsc[g]);
      wi1[g][k] = cvt8s(Wih1 + row * kH + k * 32 + grp * 8, gsc[g]);
      wh1[g][k] = cvt8s(Whh1 + row * kH + k * 32 + grp * 8, gsc[g]);
    }
#pragma unroll
    for (int i = 0; i < 3; ++i) wx[g][i] = Wih0[row * kIN + i] * gsc[g];
  }
  const float b0r  = gsc[0] * (bih0[f] + bhh0[f]);
  const float b0z  = gsc[1] * (bih0[64 + f] + bhh0[64 + f]);
  const float b0nx = gsc[2] * bih0[128 + f];
  const float b0nh = gsc[2] * bhh0[128 + f];
  const float b1r  = gsc[0] * (bih1[f] + bhh1[f]);
  const float b1z  = gsc[1] * (bih1[64 + f] + bhh1[64 + f]);
  const float b1nx = gsc[2] * bih1[128 + f];
  const float b1nh = gsc[2] * bhh1[128 + f];

  // ---- x pipeline (scalar fp32 gates, bias folded) ----
  const float* xb = x + (size_t)b * kT * kIN;
  float cx0 = xb[0], cx1 = xb[1], cx2 = xb[2];
  float gxr = fmaf(wx[0][0], cx0, fmaf(wx[0][1], cx1, fmaf(wx[0][2], cx2, b0r)));
  float gxz = fmaf(wx[1][0], cx0, fmaf(wx[1][1], cx1, fmaf(wx[1][2], cx2, b0z)));
  float gxn = fmaf(wx[2][0], cx0, fmaf(wx[2][1], cx1, fmaf(wx[2][2], cx2, b0nx)));
  float nx0 = xb[3], nx1 = xb[4], nx2 = xb[5];

  const int wadr = (4 * grp) * LDH + f;       // LDS write offset (shorts)
  const int ra0  = c * LDH + grp * 8;         // A-frag read offsets
  const int ra1  = ra0 + 32;
  float* ob = out + (size_t)b * kT * kH + f;
  const size_t FH = (size_t)kB * kT * kH;

  short8 a0 = {0, 0, 0, 0, 0, 0, 0, 0}, a1 = a0;  // h0(t-1) frags
  short8 g0 = a0, g1 = a0;                        // h1(t-2) frags
  float h0p = 0.f, h1p = 0.f;

  // ================= round 0: L0 only =================
  {
    floatx4 pr = MFMA16(a0, wh0[0][0], Z); pr = MFMA16(a1, wh0[0][1], pr);
    floatx4 pz = MFMA16(a0, wh0[1][0], Z); pz = MFMA16(a1, wh0[1][1], pz);
    floatx4 pn = MFMA16(a0, wh0[2][0], Z); pn = MFMA16(a1, wh0[2][1], pn);
    float r_ = sig2(pr[0] + gxr);
    float z_ = sig2(pz[0] + gxz);
    float u  = sig2(gxn + r_ * (pn[0] + b0nh));
    float ng = 1.0f - 2.0f * u;
    float hn = ng + z_ * (h0p - ng);
    h0p = hn;
    h0buf[0][wadr] = f2bf(hn);
    gxr = fmaf(wx[0][0], nx0, fmaf(wx[0][1], nx1, fmaf(wx[0][2], nx2, b0r)));
    gxz = fmaf(wx[1][0], nx0, fmaf(wx[1][1], nx1, fmaf(wx[1][2], nx2, b0z)));
    gxn = fmaf(wx[2][0], nx0, fmaf(wx[2][1], nx1, fmaf(wx[2][2], nx2, b0nx)));
    nx0 = xb[6]; nx1 = xb[7]; nx2 = xb[8];
    BLOCK_SYNC();
    const unsigned short* s0 = &h0buf[0][0];
    a0 = *(const short8*)(s0 + ra0); a1 = *(const short8*)(s0 + ra1);
    const unsigned short* s1 = &h1buf[0][0];  // zeros = h1(-1)
    g0 = *(const short8*)(s1 + ra0); g1 = *(const short8*)(s1 + ra1);
  }

  // ================= rounds 1..T-1 (branchless hot loop) =================
#pragma unroll 1
  for (int t = 1; t < kT; ++t) {
    // --- L0-hh on h0A (first: frags were read first after the barrier) ---
    floatx4 pr = MFMA16(a0, wh0[0][0], Z); pr = MFMA16(a1, wh0[0][1], pr);
    floatx4 pz = MFMA16(a0, wh0[1][0], Z); pz = MFMA16(a1, wh0[1][1], pz);
    floatx4 pn = MFMA16(a0, wh0[2][0], Z); pn = MFMA16(a1, wh0[2][1], pn);
    // --- L1-ih on the SAME h0A frags ---
    floatx4 qr = MFMA16(a0, wi1[0][0], Z); qr = MFMA16(a1, wi1[0][1], qr);
    floatx4 qz = MFMA16(a0, wi1[1][0], Z); qz = MFMA16(a1, wi1[1][1], qz);
    floatx4 qn = MFMA16(a0, wi1[2][0], Z); qn = MFMA16(a1, wi1[2][1], qn);
    // --- L1-hh on h1A ---
    floatx4 sr = MFMA16(g0, wh1[0][0], Z); sr = MFMA16(g1, wh1[0][1], sr);
    floatx4 sz = MFMA16(g0, wh1[1][0], Z); sz = MFMA16(g1, wh1[1][1], sz);
    floatx4 sn = MFMA16(g0, wh1[2][0], Z); sn = MFMA16(g1, wh1[2][1], sn);

    // --- L0 cell (VALU; co-issues under L1's matrix-pipe time) ---
    {
      float r_ = sig2(pr[0] + gxr);
      float z_ = sig2(pz[0] + gxz);
      float u  = sig2(gxn + r_ * (pn[0] + b0nh));
      float ng = 1.0f - 2.0f * u;
      float hn = ng + z_ * (h0p - ng);
      h0p = hn;
      h0buf[t & 1][wadr] = f2bf(hn);
    }
    // --- x gates for t+1 (unconditional; garbage at t=T-1 is never used) ---
    gxr = fmaf(wx[0][0], nx0, fmaf(wx[0][1], nx1, fmaf(wx[0][2], nx2, b0r)));
    gxz = fmaf(wx[1][0], nx0, fmaf(wx[1][1], nx1, fmaf(wx[1][2], nx2, b0z)));
    gxn = fmaf(wx[2][0], nx0, fmaf(wx[2][1], nx1, fmaf(wx[2][2], nx2, b0nx)));
    {
      const int tp = (t + 2 < kT) ? t + 2 : kT - 1;  // clamped prefetch
      const float* p = xb + (size_t)tp * kIN;
      nx0 = p[0]; nx1 = p[1]; nx2 = p[2];
    }
    // --- L1 cell -> h1(t-1) ---
    {
      float r_ = sig2(qr[0] + sr[0] + b1r);
      float z_ = sig2(qz[0] + sz[0] + b1z);
      float u  = sig2(qn[0] + b1nx + r_ * (sn[0] + b1nh));
      float ng = 1.0f - 2.0f * u;
      float hn = ng + z_ * (h1p - ng);
      h1p = hn;
      h1buf[t & 1][wadr] = f2bf(hn);
      ob[(size_t)(t - 1) * kH] = hn;  // stays in flight; no vmcnt drain
    }
    BLOCK_SYNC();
    {  // frags for round t+1: h0(t), then h1(t-1)
      const unsigned short* s0 = &h0buf[t & 1][0];
      a0 = *(const short8*)(s0 + ra0); a1 = *(const short8*)(s0 + ra1);
      const unsigned short* s1 = &h1buf[t & 1][0];
      g0 = *(const short8*)(s1 + ra0); g1 = *(const short8*)(s1 + ra1);
    }
  }

  // ================= round T: L1 only -> h1(T-1) =================
  {
    floatx4 qr = MFMA16(a0, wi1[0][0], Z); qr = MFMA16(a1, wi1[0][1], qr);
    floatx4 qz = MFMA16(a0, wi1[1][0], Z); qz = MFMA16(a1, wi1[1][1], qz);
    floatx4 qn = MFMA16(a0, wi1[2][0], Z); qn = MFMA16(a1, wi1[2][1], qn);
    floatx4 sr = MFMA16(g0, wh1[0][0], Z); sr = MFMA16(g1, wh1[0][1], sr);
    floatx4 sz = MFMA16(g0, wh1[1][0], Z); sz = MFMA16(g1, wh1[1][1], sz);
    floatx4 sn = MFMA16(g0, wh1[2][0], Z); sn = MFMA16(g1, wh1[2][1], sn);
    float r_ = sig2(qr[0] + sr[0] + b1r);
    float z_ = sig2(qz[0] + sz[0] + b1z);
    float u  = sig2(qn[0] + b1nx + r_ * (sn[0] + b1nh));
    float ng = 1.0f - 2.0f * u;
    float hn = ng + z_ * (h1p - ng);
    ob[(size_t)(kT - 1) * kH] = hn;
    out[FH + (size_t)b * kH + f] = hn;
  }
}

extern "C" void kernel_launch(void* const* d_in, const int* in_sizes, int n_in,
                              void* d_out, int out_size, void* d_ws, size_t ws_size,
                              hipStream_t stream) {
  const float* xp   = (const float*)d_in[0];
  const float* wih0 = (const float*)d_in[1];
  const float* whh0 = (const float*)d_in[2];
  const float* bih0 = (const float*)d_in[3];
  const float* bhh0 = (const float*)d_in[4];
  const float* wih1 = (const float*)d_in[5];
  const float* whh1 = (const float*)d_in[6];
  const float* bih1 = (const float*)d_in[7];
  const float* bhh1 = (const float*)d_in[8];
  float* outp = (float*)d_out;
  hipLaunchKernelGGL(gru_kernel, dim3(kB / 4), dim3(256), 0, stream,
                     xp, wih0, whh0, bih0, bhh0, wih1, whh1, bih1, bhh1, outp);
}